// Round 15
// baseline (183.315 us; speedup 1.0000x reference)
//
#include <hip/hip_runtime.h>
#include <hip/hip_bf16.h>

#define N_TOK 8192
#define C_DIM 512
#define NH 8
#define DH 64
#define KCLUST 4
#define TPF 512
#define TOPK 204
#define KVPAD 256
#define MPC 2048

// ---- workspace layout (float offsets) ----
#define WS_WQKVT  0            // w_qkv bf16 TILED [12 jt][16 sl][4096]: 786432 shorts
#define WS_WPH    393216       // w_proj bf16 (row-major, for gemm_proj)
#define WS_QHI    524288       // q hi (pre-scaled 0.125)
#define WS_KC     2621440      // compact K: 4*8*256*64 shorts
#define WS_VC     2883584      // compact V
#define WS_XAHI   3145728      // xattn hi
#define WS_XBARP  5242880      // 4*16*512
#define WS_QBAR   5275648      // 32*64
#define WS_G      5277696      // 4*512
#define WS_AGG    5279744      // 4*8192
#define WS_XT     6291456      // x bf16 TILED [128 mt][16 sl][2048]: 4194304 shorts

using frag16 = __attribute__((ext_vector_type(8))) short;
using f32x4  = __attribute__((ext_vector_type(4))) float;

__device__ __forceinline__ unsigned short f2bf(float x) {
  unsigned u = __float_as_uint(x);
  return (unsigned short)((u + 0x7fffu + ((u >> 16) & 1u)) >> 16);
}
__device__ __forceinline__ float bf2f(unsigned short h) {
  return __uint_as_float(((unsigned)h) << 16);
}
__device__ __forceinline__ unsigned pkbf(float a, float b) {
  __hip_bfloat162 t = __float22bfloat162_rn(make_float2(a, b));
  return *reinterpret_cast<unsigned*>(&t);
}

// ---------------------------------------------------------------------------
// prep_xbar (R10-validated): xbar partials. 64 blocks.
// ---------------------------------------------------------------------------
__global__ __launch_bounds__(256) void prep_xbar(
    const float* __restrict__ x, const int* __restrict__ keyframes,
    float* __restrict__ xbarp) {
  const int b = blockIdx.x, tid = threadIdx.x;
  int kk = b >> 4, s = b & 15;
  int base = keyframes[kk] * TPF + s * 32;
  float a0 = 0.f, a1 = 0.f;
  for (int t = 0; t < 32; t++) {
    a0 += x[(size_t)(base + t) * C_DIM + tid];
    a1 += x[(size_t)(base + t) * C_DIM + tid + 256];
  }
  xbarp[(kk * 16 + s) * C_DIM + tid] = a0;
  xbarp[(kk * 16 + s) * C_DIM + tid + 256] = a1;
}

// ---------------------------------------------------------------------------
// qbar_wide (R10-validated): 256 blocks, wave-parallel.
// ---------------------------------------------------------------------------
__global__ __launch_bounds__(256) void qbar_wide(
    const float* __restrict__ w_qkv, const float* __restrict__ b_qkv,
    const float* __restrict__ xbarp, float* __restrict__ qbar) {
  __shared__ float xs[C_DIM];
  const int b = blockIdx.x, tid = threadIdx.x;
  const int kk = b & 3, h = (b >> 2) & 7, dg = b >> 5;
  for (int i = tid; i < C_DIM; i += 256) {
    float a = 0.f;
    for (int s = 0; s < 16; s++) a += xbarp[(kk * 16 + s) * C_DIM + i];
    xs[i] = a * (1.f / 512.f);
  }
  __syncthreads();
  const int wave = tid >> 6, lane = tid & 63;
  const int og = wave * 2 + (lane >> 5), lt = lane & 31;
  const int d = dg * 8 + og;
  const float4* w4 =
      reinterpret_cast<const float4*>(w_qkv + (size_t)(h * 64 + d) * C_DIM + lt * 16);
  const float4* x4 = reinterpret_cast<const float4*>(&xs[lt * 16]);
  float a = 0.f;
#pragma unroll
  for (int q = 0; q < 4; q++) {
    float4 wv = w4[q], xv = x4[q];
    a += wv.x * xv.x + wv.y * xv.y + wv.z * xv.z + wv.w * xv.w;
  }
#pragma unroll
  for (int off = 16; off >= 1; off >>= 1) a += __shfl_xor(a, off);
  if (lt == 0) qbar[(h * 4 + kk) * 64 + d] = a + b_qkv[h * 64 + d];
}

// ---------------------------------------------------------------------------
// g_wide (R10-validated): 128 blocks.
// ---------------------------------------------------------------------------
__global__ __launch_bounds__(256) void g_wide(
    const float* __restrict__ w_qkv, const float* __restrict__ qbar,
    float* __restrict__ g) {
  __shared__ float qs[C_DIM];
  __shared__ float red[16][16];
  const int b = blockIdx.x, tid = threadIdx.x;
  const int kk = b >> 5, cs = b & 31;
  for (int i = tid; i < C_DIM; i += 256)
    qs[i] = qbar[((i >> 6) * 4 + kk) * 64 + (i & 63)];
  __syncthreads();
  const int jg = tid >> 4, cl = tid & 15;
  const int c = cs * 16 + cl;
  const float* wk = w_qkv + (size_t)C_DIM * C_DIM + c;
  float a = 0.f;
#pragma unroll 4
  for (int j = jg * 32; j < jg * 32 + 32; j++)
    a += qs[j] * wk[(size_t)j * C_DIM];
  red[jg][cl] = a;
  __syncthreads();
  if (tid < 16) {
    float s = red[0][tid];
#pragma unroll
    for (int q = 1; q < 16; q++) s += red[q][tid];
    g[kk * C_DIM + cs * 16 + tid] = s;
  }
}

// ---------------------------------------------------------------------------
// agg_cvt (R15): 3008 blocks.
//  [0,2048)    agg2 body (R10-verbatim)
//  [2048,2240) wqkvt cvt: w_qkv -> tiled [jt][sl][p(4)][row(128)][8] bf16
//  [2240,2496) wph cvt (row-major, R10-verbatim body)
//  [2496,3008) xt cvt: x -> tiled [mt][sl][ap(4)][row(64)][8] bf16
// Tiled images are byte-identical to the GEMM's LDS staging slabs.
// ---------------------------------------------------------------------------
__global__ __launch_bounds__(256) void agg_cvt(
    const float* __restrict__ x, const float* __restrict__ g,
    float* __restrict__ agg, const float* __restrict__ w_qkv,
    const float* __restrict__ w_proj, unsigned short* __restrict__ wqkvt,
    unsigned short* __restrict__ wph, unsigned short* __restrict__ xt) {
  __shared__ float gs[KCLUST][C_DIM];
  const int bid = blockIdx.x, tid = threadIdx.x;
  if (bid >= 2496) {
    // ---- xt cvt: 512 blocks x 4 tile-slabs ----
    int b0 = (bid - 2496) * 4;
#pragma unroll
    for (int q = 0; q < 4; q++) {
      int ts = b0 + q;                       // mt*16 + sl
      int mt = ts >> 4, sl = ts & 15;
      int row = tid & 63, ap = tid >> 6;
      const float4* src = reinterpret_cast<const float4*>(
          x + (size_t)(mt * 64 + row) * C_DIM + sl * 32 + ap * 8);
      float4 v0 = src[0], v1 = src[1];
      *reinterpret_cast<uint4*>(xt + (size_t)ts * 2048 + tid * 8) =
          make_uint4(pkbf(v0.x, v0.y), pkbf(v0.z, v0.w),
                     pkbf(v1.x, v1.y), pkbf(v1.z, v1.w));
    }
    return;
  }
  if (bid >= 2240) {
    // ---- wph cvt (row-major) ----
    int i = (bid - 2240) * 256 + tid;
    float4 v = reinterpret_cast<const float4*>(w_proj)[i];
    reinterpret_cast<uint2*>(wph)[i] = make_uint2(pkbf(v.x, v.y), pkbf(v.z, v.w));
    return;
  }
  if (bid >= 2048) {
    // ---- wqkvt cvt: 192 blocks = 12 jt x 16 sl ----
    int b = bid - 2048;
    int jt = b >> 4, sl = b & 15;
    // word0: panel p = tid>>7 (0..1), row = tid&127
    {
      int p = tid >> 7, row = tid & 127;
      const float4* src = reinterpret_cast<const float4*>(
          w_qkv + (size_t)(jt * 128 + row) * C_DIM + sl * 32 + p * 8);
      float4 v0 = src[0], v1 = src[1];
      *reinterpret_cast<uint4*>(wqkvt + (size_t)(jt * 16 + sl) * 4096 + tid * 8) =
          make_uint4(pkbf(v0.x, v0.y), pkbf(v0.z, v0.w),
                     pkbf(v1.x, v1.y), pkbf(v1.z, v1.w));
    }
    // word1: panel p = 2 + (tid>>7), row = tid&127
    {
      int p = 2 + (tid >> 7), row = tid & 127;
      const float4* src = reinterpret_cast<const float4*>(
          w_qkv + (size_t)(jt * 128 + row) * C_DIM + sl * 32 + p * 8);
      float4 v0 = src[0], v1 = src[1];
      *reinterpret_cast<uint4*>(wqkvt + (size_t)(jt * 16 + sl) * 4096 + 2048 + tid * 8) =
          make_uint4(pkbf(v0.x, v0.y), pkbf(v0.z, v0.w),
                     pkbf(v1.x, v1.y), pkbf(v1.z, v1.w));
    }
    return;
  }
  // ---- agg body (R10-verbatim) ----
  for (int i = tid; i < KCLUST * C_DIM; i += 256) gs[i >> 9][i & 511] = g[i];
  __syncthreads();
  int wave = tid >> 6, lane = tid & 63;
  int n = bid * 4 + wave;
  const float4* xp = reinterpret_cast<const float4*>(x + (size_t)n * C_DIM);
  float4 xa = xp[lane], xb = xp[lane + 64];
  float a[4];
#pragma unroll
  for (int kk = 0; kk < 4; kk++) {
    const float4* gpv = reinterpret_cast<const float4*>(&gs[kk][0]);
    float4 ga = gpv[lane], gb2 = gpv[lane + 64];
    a[kk] = xa.x * ga.x + xa.y * ga.y + xa.z * ga.z + xa.w * ga.w +
            xb.x * gb2.x + xb.y * gb2.y + xb.z * gb2.z + xb.w * gb2.w;
  }
#pragma unroll
  for (int off = 32; off >= 1; off >>= 1) {
    a[0] += __shfl_xor(a[0], off);
    a[1] += __shfl_xor(a[1], off);
    a[2] += __shfl_xor(a[2], off);
    a[3] += __shfl_xor(a[3], off);
  }
  if (lane == 0) {
    agg[0 * N_TOK + n] = a[0];
    agg[1 * N_TOK + n] = a[1];
    agg[2 * N_TOK + n] = a[2];
    agg[3 * N_TOK + n] = a[3];
  }
}

// ---------------------------------------------------------------------------
// block_scan_incl helper (R-validated; all 256 threads participate)
// ---------------------------------------------------------------------------
__device__ __forceinline__ int block_scan_incl(int v, int* wsum, int tid) {
  int lane = tid & 63, wv = tid >> 6;
#pragma unroll
  for (int off = 1; off < 64; off <<= 1) {
    int t = __shfl_up(v, off, 64);
    if (lane >= off) v += t;
  }
  if (lane == 63) wsum[wv] = v;
  __syncthreads();
  if (wv > 0) v += wsum[0];
  if (wv > 1) v += wsum[1];
  if (wv > 2) v += wsum[2];
  __syncthreads();
  return v;
}

// ---------------------------------------------------------------------------
// QKV GEMM (R15): 576 blocks, tiled-operand staging (contiguous reads).
// Blocks [0,512) = Q plane 64x128: A from xt, B from wqkvt — both tid-linear
// uint4 copies (no cvt in loop). Blocks [512,576) = compact K/V with
// in-block topk (R13-verbatim) + B from wqkvt. LDS images and MFMA sequence
// are byte-identical to R14 -> bit-identical output.
// ---------------------------------------------------------------------------
#define APAN 1032
#define BUFS 8256
__global__ __launch_bounds__(256) void gemm_qkv2(
    const float* __restrict__ x, const unsigned short* __restrict__ wqkvt,
    const unsigned short* __restrict__ xt, const float* __restrict__ bias,
    const float* __restrict__ agg, unsigned short* __restrict__ qhi,
    unsigned short* __restrict__ kc, unsigned short* __restrict__ vc) {
  __shared__ __align__(16) short pool[17828];
  const int tid = threadIdx.x;
  const int bid = blockIdx.x;
  const int wave = tid >> 6, lane = tid & 63;
  const int qd = lane >> 4, ln = lane & 15;

  if (bid < 512) {
    // ======================= Q plane, 64x128 tile =======================
    const int grp = bid >> 5;
    const int rem = bid & 31;
    const int jt = rem >> 3;                 // j0 = jt*128
    const int j0 = jt * 128;
    const int m0 = (grp * 8 + (rem & 7)) * 64;
    const int mt = m0 >> 6;
    const int rh = wave >> 1, ch = wave & 1;

    short* As = pool;            // 2 bufs x 2048 shorts
    short* Bs = pool + 4096;     // 2 bufs x 4096 shorts

    const unsigned short* pA = xt + (size_t)(mt * 16) * 2048 + tid * 8;
    const unsigned short* pB = wqkvt + (size_t)(jt * 16) * 4096 + tid * 8;

    f32x4 acc[2][4] = {};

    uint4 ra = *reinterpret_cast<const uint4*>(pA);
    uint4 rb0 = *reinterpret_cast<const uint4*>(pB);
    uint4 rb1 = *reinterpret_cast<const uint4*>(pB + 2048);
    *reinterpret_cast<uint4*>(&As[tid * 8]) = ra;
    *reinterpret_cast<uint4*>(&Bs[tid * 8]) = rb0;
    *reinterpret_cast<uint4*>(&Bs[2048 + tid * 8]) = rb1;
    __syncthreads();

    int cur = 0;
#pragma unroll
    for (int it = 0; it < 16; it++) {
      if (it < 15) {
        ra = *reinterpret_cast<const uint4*>(pA + (it + 1) * 2048);
        rb0 = *reinterpret_cast<const uint4*>(pB + (it + 1) * 4096);
        rb1 = *reinterpret_cast<const uint4*>(pB + (it + 1) * 4096 + 2048);
      }
      frag16 a_h[2], b_h[4];
#pragma unroll
      for (int i = 0; i < 2; i++)
        a_h[i] = *reinterpret_cast<const frag16*>(
            &As[cur * 2048 + qd * 512 + (rh * 32 + i * 16 + ln) * 8]);
#pragma unroll
      for (int j = 0; j < 4; j++)
        b_h[j] = *reinterpret_cast<const frag16*>(
            &Bs[cur * 4096 + qd * 1024 + (ch * 64 + j * 16 + ln) * 8]);
#pragma unroll
      for (int i = 0; i < 2; i++)
#pragma unroll
        for (int j = 0; j < 4; j++)
          acc[i][j] = __builtin_amdgcn_mfma_f32_16x16x32_bf16(a_h[i], b_h[j], acc[i][j], 0, 0, 0);
      if (it < 15) {
        int nxt = cur ^ 1;
        *reinterpret_cast<uint4*>(&As[nxt * 2048 + tid * 8]) = ra;
        *reinterpret_cast<uint4*>(&Bs[nxt * 4096 + tid * 8]) = rb0;
        *reinterpret_cast<uint4*>(&Bs[nxt * 4096 + 2048 + tid * 8]) = rb1;
        __syncthreads();
        cur = nxt;
      }
    }

    // epilogue: bf16 LDS transpose (64x136) -> coalesced qhi line writes
    __syncthreads();
    short* sh = pool;
#pragma unroll
    for (int i = 0; i < 2; i++)
#pragma unroll
      for (int j = 0; j < 4; j++) {
        int jcol = ch * 64 + j * 16 + ln;
        float bv = bias[j0 + jcol];
#pragma unroll
        for (int r = 0; r < 4; r++) {
          int mrow = rh * 32 + i * 16 + qd * 4 + r;
          sh[mrow * 136 + jcol] = (short)f2bf((acc[i][j][r] + bv) * 0.125f);
        }
      }
    __syncthreads();
#pragma unroll
    for (int p = 0; p < 4; p++) {
      int u = tid + p * 256;
      int row = u >> 4, c = (u & 15) * 8;
      int hh = ((j0 + c) >> 6) & 7, d0 = c & 63;
      *reinterpret_cast<uint4*>(qhi + ((size_t)hh * N_TOK + m0 + row) * DH + d0) =
          *reinterpret_cast<const uint4*>(&sh[row * 136 + c]);
    }
    return;
  }

  // ======================= K/V path =======================
  const int b2 = bid - 512;
  const int kk = b2 >> 4;
  const int sub = b2 & 15;
  const int mloc = (sub >> 3) * 128;
  const int jt = 4 + (sub & 7);              // j0 = 512 + (sub&7)*128
  const int j0 = jt * 128;
  const int wr = wave >> 1, wc = wave & 1;

  const int r0 = tid >> 2, p0 = tid & 3;
  const int r1 = r0 + 64;
  const float4 *pA0, *pA1;
  {
    // ---- in-block topk for cluster kk (exact topk_kernel body) ----
    unsigned* sk = reinterpret_cast<unsigned*>(pool);            // 16384 shorts
    int* hist = reinterpret_cast<int*>(pool + 16384);            // 512 shorts
    int* scn = reinterpret_cast<int*>(pool + 16896);             // 512 shorts
    int* wsum = reinterpret_cast<int*>(pool + 17408);            // 8 shorts
    int* selv = reinterpret_cast<int*>(pool + 17416);            // 4 shorts
    int* idxl = reinterpret_cast<int*>(pool + 17420);            // 408 shorts
    const float* row = agg + (size_t)kk * N_TOK;

    for (int i = tid; i < N_TOK; i += 256) {
      unsigned u = __float_as_uint(row[i]);
      sk[i] = (u & 0x80000000u) ? ~u : (u | 0x80000000u);
    }
    __syncthreads();

    unsigned prefix = 0;
    int remaining = TOPK;
#pragma unroll
    for (int rnd = 3; rnd >= 0; rnd--) {
      int shift = rnd * 8;
      hist[tid] = 0;
      __syncthreads();
      for (int i = tid; i < N_TOK; i += 256) {
        unsigned key = sk[i];
        bool in = (rnd == 3) || ((key >> (shift + 8)) == prefix);
        if (in) atomicAdd(&hist[(key >> shift) & 255], 1);
      }
      __syncthreads();
      int sv = block_scan_incl(hist[255 - tid], wsum, tid);
      scn[tid] = sv;
      __syncthreads();
      int b = tid;
      int cgt = (b == 255) ? 0 : scn[254 - b];
      if (cgt < remaining && remaining <= cgt + hist[b]) {
        selv[0] = b;
        selv[1] = remaining - cgt;
      }
      __syncthreads();
      prefix = (prefix << 8) | (unsigned)selv[0];
      remaining = selv[1];
      __syncthreads();
    }
    unsigned kth = prefix;
    int base = tid * 32;

    int cA = 0;
    for (int i = 0; i < 32; i++) cA += (sk[base + i] > kth) ? 1 : 0;
    int sA = block_scan_incl(cA, wsum, tid);
    scn[tid] = sA;
    __syncthreads();
    int exclA = sA - cA;
    int G = scn[255];
    int p = exclA;
    for (int i = 0; i < 32; i++)
      if (sk[base + i] > kth) idxl[p++] = base + i;
    __syncthreads();

    int cB = 0;
    for (int i = 0; i < 32; i++) cB += (sk[base + i] == kth) ? 1 : 0;
    int sB = block_scan_incl(cB, wsum, tid);
    int exclB = sB - cB;
    int pos = G + exclB;
    for (int i = 0; i < 32; i++) {
      if (sk[base + i] == kth) {
        if (pos < TOPK) idxl[pos] = base + i;
        pos++;
      }
    }
    __syncthreads();

    int t0i = mloc + r0, t1i = mloc + r1;
    if (t0i > TOPK - 1) t0i = TOPK - 1;
    if (t1i > TOPK - 1) t1i = TOPK - 1;
    const int tok0 = idxl[t0i];
    const int tok1 = idxl[t1i];
    __syncthreads();  // all reads done before staging overwrites pool

    pA0 = reinterpret_cast<const float4*>(x + (size_t)tok0 * C_DIM) + p0 * 2;
    pA1 = reinterpret_cast<const float4*>(x + (size_t)tok1 * C_DIM) + p0 * 2;
  }
  // B from tiled layout: slab base + panel p0, rows r0 / r1
  const unsigned short* pBt = wqkvt + (size_t)(jt * 16) * 4096;

  f32x4 acc[4][4] = {};

  float4 fa[4];
  uint4 rb[2];
  fa[0] = pA0[0]; fa[1] = pA0[1];
  fa[2] = pA1[0]; fa[3] = pA1[1];
  rb[0] = *reinterpret_cast<const uint4*>(pBt + p0 * 1024 + r0 * 8);
  rb[1] = *reinterpret_cast<const uint4*>(pBt + p0 * 1024 + r1 * 8);

  {
    *reinterpret_cast<uint4*>(&pool[p0 * APAN + r0 * 8]) =
        make_uint4(pkbf(fa[0].x, fa[0].y), pkbf(fa[0].z, fa[0].w),
                   pkbf(fa[1].x, fa[1].y), pkbf(fa[1].z, fa[1].w));
    *reinterpret_cast<uint4*>(&pool[p0 * APAN + r1 * 8]) =
        make_uint4(pkbf(fa[2].x, fa[2].y), pkbf(fa[2].z, fa[2].w),
                   pkbf(fa[3].x, fa[3].y), pkbf(fa[3].z, fa[3].w));
    *reinterpret_cast<uint4*>(&pool[4 * APAN + p0 * APAN + r0 * 8]) = rb[0];
    *reinterpret_cast<uint4*>(&pool[4 * APAN + p0 * APAN + r1 * 8]) = rb[1];
  }
  __syncthreads();

  int cur = 0;
#pragma unroll
  for (int it = 0; it < 16; it++) {
    if (it < 15) {
      int k4 = (it + 1) * 8;
      fa[0] = pA0[k4]; fa[1] = pA0[k4 + 1];
      fa[2] = pA1[k4]; fa[3] = pA1[k4 + 1];
      rb[0] = *reinterpret_cast<const uint4*>(pBt + (it + 1) * 4096 + p0 * 1024 + r0 * 8);
      rb[1] = *reinterpret_cast<const uint4*>(pBt + (it + 1) * 4096 + p0 * 1024 + r1 * 8);
    }
    const int bb = cur * BUFS;
    frag16 a_h[4], b_h[4];
#pragma unroll
    for (int i = 0; i < 4; i++) {
      int row = wr * 64 + i * 16 + ln;
      a_h[i] = *reinterpret_cast<const frag16*>(&pool[bb + qd * APAN + row * 8]);
    }
#pragma unroll
    for (int j = 0; j < 4; j++) {
      int row = wc * 64 + j * 16 + ln;
      b_h[j] = *reinterpret_cast<const frag16*>(&pool[bb + 4 * APAN + qd * APAN + row * 8]);
    }
#pragma unroll
    for (int i = 0; i < 4; i++)
#pragma unroll
      for (int j = 0; j < 4; j++)
        acc[i][j] = __builtin_amdgcn_mfma_f32_16x16x32_bf16(a_h[i], b_h[j], acc[i][j], 0, 0, 0);

    if (it < 15) {
      const int nb = (cur ^ 1) * BUFS;
      *reinterpret_cast<uint4*>(&pool[nb + p0 * APAN + r0 * 8]) =
          make_uint4(pkbf(fa[0].x, fa[0].y), pkbf(fa[0].z, fa[0].w),
                     pkbf(fa[1].x, fa[1].y), pkbf(fa[1].z, fa[1].w));
      *reinterpret_cast<uint4*>(&pool[nb + p0 * APAN + r1 * 8]) =
          make_uint4(pkbf(fa[2].x, fa[2].y), pkbf(fa[2].z, fa[2].w),
                     pkbf(fa[3].x, fa[3].y), pkbf(fa[3].z, fa[3].w));
      *reinterpret_cast<uint4*>(&pool[nb + 4 * APAN + p0 * APAN + r0 * 8]) = rb[0];
      *reinterpret_cast<uint4*>(&pool[nb + 4 * APAN + p0 * APAN + r1 * 8]) = rb[1];
    }
    __syncthreads();
    cur ^= 1;
  }

  // ---- epilogue: LDS transpose (128x136) -> coalesced kc/vc writes ----
  const int sel = j0 >> 9;  // 1 = K, 2 = V
  short* sh = pool;
#pragma unroll
  for (int i = 0; i < 4; i++)
#pragma unroll
    for (int j = 0; j < 4; j++) {
      int jcol = wc * 64 + j * 16 + ln;
      float bv = bias[j0 + jcol];
#pragma unroll
      for (int r = 0; r < 4; r++) {
        int mrow = wr * 64 + i * 16 + qd * 4 + r;
        sh[mrow * 136 + jcol] = (short)f2bf(acc[i][j][r] + bv);
      }
    }
  __syncthreads();
  unsigned short* dstc = (sel == 1) ? kc : vc;
#pragma unroll
  for (int p = 0; p < 8; p++) {
    int u = tid + p * 256;
    int row = u >> 4, c = (u & 15) * 8;
    int hh = ((j0 + c) >> 6) & 7, d0 = c & 63;
    *reinterpret_cast<uint4*>(
        dstc + (((size_t)kk * 8 + hh) * KVPAD + mloc + row) * DH + d0) =
        *reinterpret_cast<const uint4*>(&sh[row * 136 + c]);
  }
}

// ---------------------------------------------------------------------------
// MFMA flash attention (R5/R10-validated): static tail, compact K/V.
// ---------------------------------------------------------------------------
__global__ __launch_bounds__(256) void flash_mfma(
    const unsigned short* __restrict__ qhi, const unsigned short* __restrict__ kc,
    const unsigned short* __restrict__ vc, const int* __restrict__ clusters,
    unsigned short* __restrict__ xahi) {
  __shared__ short Ks[64 * 72];
  __shared__ short Vs[64 * 72];
  __shared__ short Ps[128 * 72];
  const int tid = threadIdx.x;
  const int qb = blockIdx.x, kk = blockIdx.y, h = blockIdx.z;
  const int wave = tid >> 6, lane = tid & 63;
  const int ln = lane & 15, qd = lane >> 4;

  const int q_local0 = qb * 128;
  const int frame = clusters[kk * 4 + (q_local0 >> 9)];
  const int tokbase = frame * TPF + (q_local0 & 511);
  const size_t kvbase = ((size_t)kk * 8 + h) * KVPAD * DH;

  frag16 qa_h[2][2];
#pragma unroll
  for (int mt = 0; mt < 2; mt++) {
    const int tok_m = tokbase + wave * 32 + mt * 16 + ln;
    const unsigned short* qr_h = qhi + ((size_t)h * N_TOK + tok_m) * DH;
#pragma unroll
    for (int s = 0; s < 2; s++)
      qa_h[mt][s] = *reinterpret_cast<const frag16*>(qr_h + s * 32 + qd * 8);
  }

  f32x4 acc_o[2][4] = {};
  float lsum[2][4] = {};

  for (int t0 = 0; t0 < 192; t0 += 64) {
#pragma unroll
    for (int i = 0; i < 2; i++) {
      int u = tid + i * 256;
      int r = u >> 3, oct = u & 7;
      *reinterpret_cast<frag16*>(&Ks[r * 72 + oct * 8]) =
          *reinterpret_cast<const frag16*>(kc + kvbase + (size_t)(t0 + r) * DH + oct * 8);
    }
    {
      int tk = (tid & 15) * 4, td = (tid >> 4) * 4;
      uint2 w2[4];
#pragma unroll
      for (int i = 0; i < 4; i++)
        w2[i] = *reinterpret_cast<const uint2*>(vc + kvbase + (size_t)(t0 + tk + i) * DH + td);
#pragma unroll
      for (int dd = 0; dd < 4; dd++) {
        unsigned s0 = (dd < 2) ? (w2[0].x >> (16 * dd)) : (w2[0].y >> (16 * (dd - 2)));
        unsigned s1 = (dd < 2) ? (w2[1].x >> (16 * dd)) : (w2[1].y >> (16 * (dd - 2)));
        unsigned s2 = (dd < 2) ? (w2[2].x >> (16 * dd)) : (w2[2].y >> (16 * (dd - 2)));
        unsigned s3 = (dd < 2) ? (w2[3].x >> (16 * dd)) : (w2[3].y >> (16 * (dd - 2)));
        *reinterpret_cast<uint2*>(&Vs[(td + dd) * 72 + tk]) =
            make_uint2((s0 & 0xffffu) | (s1 << 16), (s2 & 0xffffu) | (s3 << 16));
      }
    }
    __syncthreads();

#pragma unroll
    for (int mt = 0; mt < 2; mt++) {
      f32x4 sacc[4] = {};
#pragma unroll
      for (int c = 0; c < 4; c++) {
#pragma unroll
        for (int s = 0; s < 2; s++) {
          frag16 bh = *reinterpret_cast<const frag16*>(&Ks[(c * 16 + ln) * 72 + s * 32 + qd * 8]);
          sacc[c] = __builtin_amdgcn_mfma_f32_16x16x32_bf16(qa_h[mt][s], bh, sacc[c], 0, 0, 0);
        }
      }
#pragma unroll
      for (int c = 0; c < 4; c++) {
#pragma unroll
        for (int r = 0; r < 4; r++) {
          float p = __expf(sacc[c][r]);
          lsum[mt][r] += p;
          Ps[(wave * 32 + mt * 16 + qd * 4 + r) * 72 + c * 16 + ln] = (short)f2bf(p);
        }
      }
    }

#pragma unroll
    for (int mt = 0; mt < 2; mt++)
#pragma unroll
      for (int s = 0; s < 2; s++) {
        frag16 pa = *reinterpret_cast<const frag16*>(
            &Ps[(wave * 32 + mt * 16 + ln) * 72 + s * 32 + qd * 8]);
#pragma unroll
        for (int dt = 0; dt < 4; dt++) {
          frag16 vb = *reinterpret_cast<const frag16*>(&Vs[(dt * 16 + ln) * 72 + s * 32 + qd * 8]);
          acc_o[mt][dt] = __builtin_amdgcn_mfma_f32_16x16x32_bf16(pa, vb, acc_o[mt][dt], 0, 0, 0);
        }
      }
    __syncthreads();
  }

  {
    const int t0 = 192;
#pragma unroll
    for (int i = 0; i < 2; i++) {
      int u = tid + i * 256;
      int r = u >> 3, oct = u & 7;
      *reinterpret_cast<frag16*>(&Ks[r * 72 + oct * 8]) =
          *reinterpret_cast<const frag16*>(kc + kvbase + (size_t)(t0 + r) * DH + oct * 8);
    }
    {
      int tk = (tid & 15) * 4, td = (tid >> 4) * 4;
      uint2 w2[4];
#pragma unroll
      for (int i = 0; i < 4; i++)
        w2[i] = *reinterpret_cast<const uint2*>(vc + kvbase + (size_t)(t0 + tk + i) * DH + td);
#pragma unroll
      for (int dd = 0; dd < 4; dd++) {
        unsigned s0 = (dd < 2) ? (w2[0].x >> (16 * dd)) : (w2[0].y >> (16 * (dd - 2)));
        unsigned s1 = (dd < 2) ? (w2[1].x >> (16 * dd)) : (w2[1].y >> (16 * (dd - 2)));
        unsigned s2 = (dd < 2) ? (w2[2].x >> (16 * dd)) : (w2[2].y >> (16 * (dd - 2)));
        unsigned s3 = (dd < 2) ? (w2[3].x >> (16 * dd)) : (w2[3].y >> (16 * (dd - 2)));
        *reinterpret_cast<uint2*>(&Vs[(td + dd) * 72 + tk]) =
            make_uint2((s0 & 0xffffu) | (s1 << 16), (s2 & 0xffffu) | (s3 << 16));
      }
    }
    __syncthreads();

#pragma unroll
    for (int mt = 0; mt < 2; mt++) {
      f32x4 sacc = {};
#pragma unroll
      for (int s = 0; s < 2; s++) {
        frag16 bh = *reinterpret_cast<const frag16*>(&Ks[ln * 72 + s * 32 + qd * 8]);
        sacc = __builtin_amdgcn_mfma_f32_16x16x32_bf16(qa_h[mt][s], bh, sacc, 0, 0, 0);
      }
#pragma unroll
      for (int r = 0; r < 4; r++) {
        float p = (ln < 12) ? __expf(sacc[r]) : 0.f;
        lsum[mt][r] += p;
        int prow = (wave * 32 + mt * 16 + qd * 4 + r) * 72;
        Ps[prow + ln] = (short)f2bf(p);
        Ps[prow + 16 + ln] = 0;
      }
    }

#pragma unroll
    for (int mt = 0; mt < 2; mt++) {
      frag16 pa = *reinterpret_cast<const frag16*>(
          &Ps[(wave * 32 + mt * 16 + ln) * 72 + qd * 8]);
#pragma unroll
      for (int dt = 0; dt < 4; dt++) {
        frag16 vb = *reinterpret_cast<const frag16*>(&Vs[(dt * 16 + ln) * 72 + qd * 8]);
        acc_o[mt][dt] = __builtin_amdgcn_mfma_f32_16x16x32_bf16(pa, vb, acc_o[mt][dt], 0, 0, 0);
      }
    }
  }

#pragma unroll
  for (int mt = 0; mt < 2; mt++)
#pragma unroll
    for (int r = 0; r < 4; r++) {
      float l = lsum[mt][r];
      l += __shfl_xor(l, 1);
      l += __shfl_xor(l, 2);
      l += __shfl_xor(l, 4);
      l += __shfl_xor(l, 8);
      lsum[mt][r] = 1.f / l;
    }

#pragma unroll
  for (int mt = 0; mt < 2; mt++)
#pragma unroll
    for (int dt = 0; dt < 4; dt++)
#pragma unroll
      for (int r = 0; r < 4; r++)
        Ps[(wave * 32 + mt * 16 + qd * 4 + r) * 72 + dt * 16 + ln] =
            (short)f2bf(acc_o[mt][dt][r] * lsum[mt][r]);
  __syncthreads();
#pragma unroll
  for (int p = 0; p < 4; p++) {
    int u = tid + p * 256;
    int row = u >> 3, c = (u & 7) * 8;
    *reinterpret_cast<uint4*>(xahi + (size_t)(tokbase + row) * C_DIM + h * DH + c) =
        *reinterpret_cast<const uint4*>(&Ps[row * 72 + c]);
  }
}

// ---------------------------------------------------------------------------
// Projection GEMM (R5/R10-validated): 64x128, reg-dbuf, 512 blocks.
// ---------------------------------------------------------------------------
__global__ __launch_bounds__(256) void gemm_proj(
    const unsigned short* __restrict__ Ahi, const unsigned short* __restrict__ Bhi,
    const float* __restrict__ bias, float* __restrict__ out) {
  __shared__ short pool[12288];
  short* As = pool;
  short* Bs = pool + 4096;
  const int tid = threadIdx.x;
  const int bid = blockIdx.x;
  const int grp = bid / 32;
  const int rem = bid - grp * 32;
  const int jblk = rem >> 3;
  const int m_idx = grp * 8 + (rem & 7);
  const int j0 = jblk * 128;
  const int m0 = m_idx * 64;
  const int wave = tid >> 6, lane = tid & 63;
  const int rh = wave >> 1, ch = wave & 1;
  const int qd = lane >> 4, ln = lane & 15;

  const int arow = tid & 63, ap = tid >> 6;
  const int brow = tid & 127, bp = tid >> 7;
  const unsigned short* pA = Ahi + (size_t)(m0 + arow) * C_DIM + ap * 8;
  const unsigned short* pB0 = Bhi + (size_t)(j0 + brow) * C_DIM + bp * 8;
  const unsigned short* pB1 = pB0 + 16;

  f32x4 acc[2][4] = {};

  uint4 ra = *reinterpret_cast<const uint4*>(pA);
  uint4 rb0 = *reinterpret_cast<const uint4*>(pB0);
  uint4 rb1 = *reinterpret_cast<const uint4*>(pB1);
  *reinterpret_cast<uint4*>(&As[ap * 512 + arow * 8]) = ra;
  *reinterpret_cast<uint4*>(&Bs[bp * 1024 + brow * 8]) = rb0;
  *reinterpret_cast<uint4*>(&Bs[(bp + 2) * 1024 + brow * 8]) = rb1;
  __syncthreads();

  int cur = 0;
#pragma unroll
  for (int it = 0; it < 16; it++) {
    if (it < 15) {
      int k = (it + 1) * 32;
      ra = *reinterpret_cast<const uint4*>(pA + k);
      rb0 = *reinterpret_cast<const uint4*>(pB0 + k);
      rb1 = *reinterpret_cast<const uint4*>(pB1 + k);
    }
    frag16 a_h[2], b_h[4];
#pragma unroll
    for (int i = 0; i < 2; i++)
      a_h[i] = *reinterpret_cast<const frag16*>(&As[cur * 2048 + qd * 512 + (rh * 32 + i * 16 + ln) * 8]);
#pragma unroll
    for (int j = 0; j < 4; j++)
      b_h[j] = *reinterpret_cast<const frag16*>(&Bs[cur * 4096 + qd * 1024 + (ch * 64 + j * 16 + ln) * 8]);
#pragma unroll
    for (int i = 0; i < 2; i++)
#pragma unroll
      for (int j = 0; j < 4; j++)
        acc[i][j] = __builtin_amdgcn_mfma_f32_16x16x32_bf16(a_h[i], b_h[j], acc[i][j], 0, 0, 0);
    if (it < 15) {
      int nxt = cur ^ 1;
      *reinterpret_cast<uint4*>(&As[nxt * 2048 + ap * 512 + arow * 8]) = ra;
      *reinterpret_cast<uint4*>(&Bs[nxt * 4096 + bp * 1024 + brow * 8]) = rb0;
      *reinterpret_cast<uint4*>(&Bs[nxt * 4096 + (bp + 2) * 1024 + brow * 8]) = rb1;
      __syncthreads();
      cur = nxt;
    }
  }

  float* sh32 = reinterpret_cast<float*>(pool);  // 64 x 68
#pragma unroll
  for (int chp = 0; chp < 2; chp++) {
    __syncthreads();
    if (ch == chp) {
#pragma unroll
      for (int i = 0; i < 2; i++)
#pragma unroll
        for (int j = 0; j < 4; j++) {
          int jcol = j * 16 + ln;
          float bv = bias[j0 + chp * 64 + jcol];
#pragma unroll
          for (int r = 0; r < 4; r++)
            sh32[(rh * 32 + i * 16 + qd * 4 + r) * 68 + jcol] = acc[i][j][r] + bv;
        }
    }
    __syncthreads();
#pragma unroll
    for (int p = 0; p < 4; p++) {
      int u = tid + p * 256;
      int row = u >> 4, c4 = (u & 15) * 4;
      *reinterpret_cast<float4*>(out + (size_t)(m0 + row) * C_DIM + j0 + chp * 64 + c4) =
          *reinterpret_cast<const float4*>(&sh32[row * 68 + c4]);
    }
  }
}

// ---------------------------------------------------------------------------
extern "C" void kernel_launch(void* const* d_in, const int* in_sizes, int n_in,
                              void* d_out, int out_size, void* d_ws, size_t ws_size,
                              hipStream_t stream) {
  const float* x = (const float*)d_in[0];
  const float* w_qkv = (const float*)d_in[1];
  const float* b_qkv = (const float*)d_in[2];
  const float* w_proj = (const float*)d_in[3];
  const float* b_proj = (const float*)d_in[4];
  const int* keyframes = (const int*)d_in[5];
  const int* clusters = (const int*)d_in[6];
  float* out = (float*)d_out;
  float* ws = (float*)d_ws;

  unsigned short* wqkvt = (unsigned short*)(ws + WS_WQKVT);
  unsigned short* wph = (unsigned short*)(ws + WS_WPH);
  unsigned short* qhi = (unsigned short*)(ws + WS_QHI);
  unsigned short* kc = (unsigned short*)(ws + WS_KC);
  unsigned short* vc = (unsigned short*)(ws + WS_VC);
  unsigned short* xahi = (unsigned short*)(ws + WS_XAHI);
  unsigned short* xt = (unsigned short*)(ws + WS_XT);
  float* xbarp = ws + WS_XBARP;
  float* qbar = ws + WS_QBAR;
  float* g = ws + WS_G;
  float* agg = ws + WS_AGG;

  // 1. xbar partials (64 blocks)
  prep_xbar<<<64, 256, 0, stream>>>(x, keyframes, xbarp);
  // 2. qbar, wave-parallel (256 blocks)
  qbar_wide<<<256, 256, 0, stream>>>(w_qkv, b_qkv, xbarp, qbar);
  // 3. g, parallel (128 blocks)
  g_wide<<<128, 256, 0, stream>>>(w_qkv, qbar, g);
  // 4. agg (2048) + wqkvt tiled cvt (192) + wph cvt (256) + xt cvt (512)
  agg_cvt<<<3008, 256, 0, stream>>>(x, g, agg, w_qkv, w_proj, wqkvt, wph, xt);
  // 5. Q GEMM (tiled operands) + KV GEMM with in-block topk
  gemm_qkv2<<<576, 256, 0, stream>>>(x, wqkvt, xt, b_qkv, agg, qhi, kc, vc);
  // 6. fused MFMA attention
  flash_mfma<<<dim3(MPC / 128, KCLUST, NH), 256, 0, stream>>>(
      qhi, kc, vc, clusters, xahi);
  // 7. projection GEMM
  gemm_proj<<<512, 256, 0, stream>>>(xahi, wph, b_proj, out);
}

// Round 16
// 165.218 us; speedup vs baseline: 1.1095x; 1.1095x over previous
//
#include <hip/hip_runtime.h>
#include <hip/hip_bf16.h>

#define N_TOK 8192
#define C_DIM 512
#define NH 8
#define DH 64
#define KCLUST 4
#define TPF 512
#define TOPK 204
#define KVPAD 256
#define MPC 2048

// ---- workspace layout (float offsets) ----
#define WS_WQH    0            // w_qkv bf16: 786432 shorts
#define WS_WPH    393216       // w_proj bf16
#define WS_QHI    524288       // q hi (pre-scaled 0.125)
#define WS_KC     2621440      // compact K: 4*8*256*64 shorts
#define WS_VC     2883584      // compact V
#define WS_XAHI   3145728      // xattn hi
#define WS_XBARP  5242880      // 4*16*512
#define WS_QBAR   5275648      // 32*64
#define WS_G      5277696      // 4*512
#define WS_AGG    5279744      // 4*8192

using frag16 = __attribute__((ext_vector_type(8))) short;
using f32x4  = __attribute__((ext_vector_type(4))) float;

__device__ __forceinline__ unsigned short f2bf(float x) {
  unsigned u = __float_as_uint(x);
  return (unsigned short)((u + 0x7fffu + ((u >> 16) & 1u)) >> 16);
}
__device__ __forceinline__ float bf2f(unsigned short h) {
  return __uint_as_float(((unsigned)h) << 16);
}
__device__ __forceinline__ unsigned pkbf(float a, float b) {
  __hip_bfloat162 t = __float22bfloat162_rn(make_float2(a, b));
  return *reinterpret_cast<unsigned*>(&t);
}

// ---------------------------------------------------------------------------
// prep_xbar (R10-validated): xbar partials. 64 blocks.
// ---------------------------------------------------------------------------
__global__ __launch_bounds__(256) void prep_xbar(
    const float* __restrict__ x, const int* __restrict__ keyframes,
    float* __restrict__ xbarp) {
  const int b = blockIdx.x, tid = threadIdx.x;
  int kk = b >> 4, s = b & 15;
  int base = keyframes[kk] * TPF + s * 32;
  float a0 = 0.f, a1 = 0.f;
  for (int t = 0; t < 32; t++) {
    a0 += x[(size_t)(base + t) * C_DIM + tid];
    a1 += x[(size_t)(base + t) * C_DIM + tid + 256];
  }
  xbarp[(kk * 16 + s) * C_DIM + tid] = a0;
  xbarp[(kk * 16 + s) * C_DIM + tid + 256] = a1;
}

// ---------------------------------------------------------------------------
// qbar_wide (R10-validated): 256 blocks, wave-parallel.
// ---------------------------------------------------------------------------
__global__ __launch_bounds__(256) void qbar_wide(
    const float* __restrict__ w_qkv, const float* __restrict__ b_qkv,
    const float* __restrict__ xbarp, float* __restrict__ qbar) {
  __shared__ float xs[C_DIM];
  const int b = blockIdx.x, tid = threadIdx.x;
  const int kk = b & 3, h = (b >> 2) & 7, dg = b >> 5;
  for (int i = tid; i < C_DIM; i += 256) {
    float a = 0.f;
    for (int s = 0; s < 16; s++) a += xbarp[(kk * 16 + s) * C_DIM + i];
    xs[i] = a * (1.f / 512.f);
  }
  __syncthreads();
  const int wave = tid >> 6, lane = tid & 63;
  const int og = wave * 2 + (lane >> 5), lt = lane & 31;
  const int d = dg * 8 + og;
  const float4* w4 =
      reinterpret_cast<const float4*>(w_qkv + (size_t)(h * 64 + d) * C_DIM + lt * 16);
  const float4* x4 = reinterpret_cast<const float4*>(&xs[lt * 16]);
  float a = 0.f;
#pragma unroll
  for (int q = 0; q < 4; q++) {
    float4 wv = w4[q], xv = x4[q];
    a += wv.x * xv.x + wv.y * xv.y + wv.z * xv.z + wv.w * xv.w;
  }
#pragma unroll
  for (int off = 16; off >= 1; off >>= 1) a += __shfl_xor(a, off);
  if (lt == 0) qbar[(h * 4 + kk) * 64 + d] = a + b_qkv[h * 64 + d];
}

// ---------------------------------------------------------------------------
// g_wide (R10-validated): 128 blocks.
// ---------------------------------------------------------------------------
__global__ __launch_bounds__(256) void g_wide(
    const float* __restrict__ w_qkv, const float* __restrict__ qbar,
    float* __restrict__ g) {
  __shared__ float qs[C_DIM];
  __shared__ float red[16][16];
  const int b = blockIdx.x, tid = threadIdx.x;
  const int kk = b >> 5, cs = b & 31;
  for (int i = tid; i < C_DIM; i += 256)
    qs[i] = qbar[((i >> 6) * 4 + kk) * 64 + (i & 63)];
  __syncthreads();
  const int jg = tid >> 4, cl = tid & 15;
  const int c = cs * 16 + cl;
  const float* wk = w_qkv + (size_t)C_DIM * C_DIM + c;
  float a = 0.f;
#pragma unroll 4
  for (int j = jg * 32; j < jg * 32 + 32; j++)
    a += qs[j] * wk[(size_t)j * C_DIM];
  red[jg][cl] = a;
  __syncthreads();
  if (tid < 16) {
    float s = red[0][tid];
#pragma unroll
    for (int q = 1; q < 16; q++) s += red[q][tid];
    g[kk * C_DIM + cs * 16 + tid] = s;
  }
}

// ---------------------------------------------------------------------------
// agg_wcvt (R10-validated): blocks [0,2048) = agg2 body; [2048,3072) = cvt.
// ---------------------------------------------------------------------------
__global__ __launch_bounds__(256) void agg_wcvt(
    const float* __restrict__ x, const float* __restrict__ g,
    float* __restrict__ agg, const float* __restrict__ w_qkv,
    const float* __restrict__ w_proj, unsigned short* __restrict__ wqh,
    unsigned short* __restrict__ wph) {
  __shared__ float gs[KCLUST][C_DIM];
  const int bid = blockIdx.x, tid = threadIdx.x;
  if (bid >= 2048) {
    int bx = bid - 2048;
    const float* src = (bx < 768) ? w_qkv : w_proj;
    unsigned short* dst = (bx < 768) ? wqh : wph;
    int i = ((bx < 768) ? bx : (bx - 768)) * 256 + tid;
    float4 v = reinterpret_cast<const float4*>(src)[i];
    reinterpret_cast<uint2*>(dst)[i] = make_uint2(pkbf(v.x, v.y), pkbf(v.z, v.w));
    return;
  }
  for (int i = tid; i < KCLUST * C_DIM; i += 256) gs[i >> 9][i & 511] = g[i];
  __syncthreads();
  int wave = tid >> 6, lane = tid & 63;
  int n = bid * 4 + wave;
  const float4* xp = reinterpret_cast<const float4*>(x + (size_t)n * C_DIM);
  float4 xa = xp[lane], xb = xp[lane + 64];
  float a[4];
#pragma unroll
  for (int kk = 0; kk < 4; kk++) {
    const float4* gpv = reinterpret_cast<const float4*>(&gs[kk][0]);
    float4 ga = gpv[lane], gb2 = gpv[lane + 64];
    a[kk] = xa.x * ga.x + xa.y * ga.y + xa.z * ga.z + xa.w * ga.w +
            xb.x * gb2.x + xb.y * gb2.y + xb.z * gb2.z + xb.w * gb2.w;
  }
#pragma unroll
  for (int off = 32; off >= 1; off >>= 1) {
    a[0] += __shfl_xor(a[0], off);
    a[1] += __shfl_xor(a[1], off);
    a[2] += __shfl_xor(a[2], off);
    a[3] += __shfl_xor(a[3], off);
  }
  if (lane == 0) {
    agg[0 * N_TOK + n] = a[0];
    agg[1 * N_TOK + n] = a[1];
    agg[2 * N_TOK + n] = a[2];
    agg[3 * N_TOK + n] = a[3];
  }
}

// ---------------------------------------------------------------------------
// block_scan_incl helper (R-validated; all 256 threads participate)
// ---------------------------------------------------------------------------
__device__ __forceinline__ int block_scan_incl(int v, int* wsum, int tid) {
  int lane = tid & 63, wv = tid >> 6;
#pragma unroll
  for (int off = 1; off < 64; off <<= 1) {
    int t = __shfl_up(v, off, 64);
    if (lane >= off) v += t;
  }
  if (lane == 63) wsum[wv] = v;
  __syncthreads();
  if (wv > 0) v += wsum[0];
  if (wv > 1) v += wsum[1];
  if (wv > 2) v += wsum[2];
  __syncthreads();
  return v;
}

// ---------------------------------------------------------------------------
// QKV GEMM (R16): 640 blocks. Blocks [0,512) = Q plane 64x128 (R14-verbatim).
// Blocks [512,640) = compact K/V SPLIT to 64x128 tiles (4 row-tiles x 8
// col-tiles x 4 clusters): in-block topk (R13-verbatim) + Q-path-style
// acc[2][4] pipeline with topk-gathered A rows. Same staged bits and K-order
// -> bit-identical kc/vc; halves the KV-block serial GEMM critical path.
// ---------------------------------------------------------------------------
__global__ __launch_bounds__(256) void gemm_qkv2(
    const float* __restrict__ x, const unsigned short* __restrict__ Bhi,
    const float* __restrict__ bias, const float* __restrict__ agg,
    unsigned short* __restrict__ qhi, unsigned short* __restrict__ kc,
    unsigned short* __restrict__ vc) {
  // LDS union: GEMM staging (12288 shorts) OR topk scratch (17828 shorts).
  __shared__ __align__(16) short pool[17828];
  const int tid = threadIdx.x;
  const int bid = blockIdx.x;
  const int wave = tid >> 6, lane = tid & 63;
  const int qd = lane >> 4, ln = lane & 15;
  const int rh = wave >> 1, ch = wave & 1;

  const bool is_kv = bid >= 512;
  int j0, m0 = 0, kk = 0, mloc = 0;
  if (!is_kv) {
    const int grp = bid >> 5;
    const int rem = bid & 31;
    j0 = (rem >> 3) * 128;
    m0 = (grp * 8 + (rem & 7)) * 64;
  } else {
    const int b2 = bid - 512;
    kk = b2 >> 5;
    const int sub = b2 & 31;
    mloc = (sub >> 3) * 64;
    j0 = 512 + (sub & 7) * 128;
  }

  short* As = pool;            // 2 bufs x 2048 shorts
  short* Bs = pool + 4096;     // 2 bufs x 4096 shorts

  const int arow = tid & 63, ap = tid >> 6;
  const int brow = tid & 127, bp = tid >> 7;

  const float4* pA4;
  if (!is_kv) {
    pA4 = reinterpret_cast<const float4*>(x + (size_t)(m0 + arow) * C_DIM) + ap * 2;
  } else {
    // ---- in-block topk for cluster kk (exact topk_kernel body) ----
    unsigned* sk = reinterpret_cast<unsigned*>(pool);            // 16384 shorts
    int* hist = reinterpret_cast<int*>(pool + 16384);            // 512 shorts
    int* scn = reinterpret_cast<int*>(pool + 16896);             // 512 shorts
    int* wsum = reinterpret_cast<int*>(pool + 17408);            // 8 shorts
    int* selv = reinterpret_cast<int*>(pool + 17416);            // 4 shorts
    int* idxl = reinterpret_cast<int*>(pool + 17420);            // 408 shorts
    const float* row = agg + (size_t)kk * N_TOK;

    for (int i = tid; i < N_TOK; i += 256) {
      unsigned u = __float_as_uint(row[i]);
      sk[i] = (u & 0x80000000u) ? ~u : (u | 0x80000000u);
    }
    __syncthreads();

    unsigned prefix = 0;
    int remaining = TOPK;
#pragma unroll
    for (int rnd = 3; rnd >= 0; rnd--) {
      int shift = rnd * 8;
      hist[tid] = 0;
      __syncthreads();
      for (int i = tid; i < N_TOK; i += 256) {
        unsigned key = sk[i];
        bool in = (rnd == 3) || ((key >> (shift + 8)) == prefix);
        if (in) atomicAdd(&hist[(key >> shift) & 255], 1);
      }
      __syncthreads();
      int sv = block_scan_incl(hist[255 - tid], wsum, tid);
      scn[tid] = sv;
      __syncthreads();
      int b = tid;
      int cgt = (b == 255) ? 0 : scn[254 - b];
      if (cgt < remaining && remaining <= cgt + hist[b]) {
        selv[0] = b;
        selv[1] = remaining - cgt;
      }
      __syncthreads();
      prefix = (prefix << 8) | (unsigned)selv[0];
      remaining = selv[1];
      __syncthreads();
    }
    unsigned kth = prefix;
    int base = tid * 32;

    int cA = 0;
    for (int i = 0; i < 32; i++) cA += (sk[base + i] > kth) ? 1 : 0;
    int sA = block_scan_incl(cA, wsum, tid);
    scn[tid] = sA;
    __syncthreads();
    int exclA = sA - cA;
    int G = scn[255];
    int p = exclA;
    for (int i = 0; i < 32; i++)
      if (sk[base + i] > kth) idxl[p++] = base + i;
    __syncthreads();

    int cB = 0;
    for (int i = 0; i < 32; i++) cB += (sk[base + i] == kth) ? 1 : 0;
    int sB = block_scan_incl(cB, wsum, tid);
    int exclB = sB - cB;
    int pos = G + exclB;
    for (int i = 0; i < 32; i++) {
      if (sk[base + i] == kth) {
        if (pos < TOPK) idxl[pos] = base + i;
        pos++;
      }
    }
    __syncthreads();

    int ti = mloc + arow;
    if (ti > TOPK - 1) ti = TOPK - 1;
    const int tok = idxl[ti];
    __syncthreads();  // all reads done before staging overwrites pool

    pA4 = reinterpret_cast<const float4*>(x + (size_t)tok * C_DIM) + ap * 2;
  }
  const unsigned short* pB0 = Bhi + (size_t)(j0 + brow) * C_DIM + bp * 8;
  const unsigned short* pB1 = pB0 + 16;

  f32x4 acc[2][4] = {};

  float4 fa0 = pA4[0], fa1 = pA4[1];
  uint4 rb0 = *reinterpret_cast<const uint4*>(pB0);
  uint4 rb1 = *reinterpret_cast<const uint4*>(pB1);
  *reinterpret_cast<uint4*>(&As[ap * 512 + arow * 8]) =
      make_uint4(pkbf(fa0.x, fa0.y), pkbf(fa0.z, fa0.w),
                 pkbf(fa1.x, fa1.y), pkbf(fa1.z, fa1.w));
  *reinterpret_cast<uint4*>(&Bs[bp * 1024 + brow * 8]) = rb0;
  *reinterpret_cast<uint4*>(&Bs[(bp + 2) * 1024 + brow * 8]) = rb1;
  __syncthreads();

  int cur = 0;
#pragma unroll
  for (int it = 0; it < 16; it++) {
    if (it < 15) {
      int k4 = (it + 1) * 8;
      fa0 = pA4[k4];
      fa1 = pA4[k4 + 1];
      rb0 = *reinterpret_cast<const uint4*>(pB0 + (it + 1) * 32);
      rb1 = *reinterpret_cast<const uint4*>(pB1 + (it + 1) * 32);
    }
    frag16 a_h[2], b_h[4];
#pragma unroll
    for (int i = 0; i < 2; i++)
      a_h[i] = *reinterpret_cast<const frag16*>(
          &As[cur * 2048 + qd * 512 + (rh * 32 + i * 16 + ln) * 8]);
#pragma unroll
    for (int j = 0; j < 4; j++)
      b_h[j] = *reinterpret_cast<const frag16*>(
          &Bs[cur * 4096 + qd * 1024 + (ch * 64 + j * 16 + ln) * 8]);
#pragma unroll
    for (int i = 0; i < 2; i++)
#pragma unroll
      for (int j = 0; j < 4; j++)
        acc[i][j] = __builtin_amdgcn_mfma_f32_16x16x32_bf16(a_h[i], b_h[j], acc[i][j], 0, 0, 0);
    if (it < 15) {
      int nxt = cur ^ 1;
      *reinterpret_cast<uint4*>(&As[nxt * 2048 + ap * 512 + arow * 8]) =
          make_uint4(pkbf(fa0.x, fa0.y), pkbf(fa0.z, fa0.w),
                     pkbf(fa1.x, fa1.y), pkbf(fa1.z, fa1.w));
      *reinterpret_cast<uint4*>(&Bs[nxt * 4096 + bp * 1024 + brow * 8]) = rb0;
      *reinterpret_cast<uint4*>(&Bs[nxt * 4096 + (bp + 2) * 1024 + brow * 8]) = rb1;
      __syncthreads();
      cur = nxt;
    }
  }

  // ---- epilogue: bf16 LDS transpose (64x136) -> coalesced line writes ----
  __syncthreads();
  short* sh = pool;
  const float qscale = (!is_kv) ? 0.125f : 1.0f;
#pragma unroll
  for (int i = 0; i < 2; i++)
#pragma unroll
    for (int j = 0; j < 4; j++) {
      int jcol = ch * 64 + j * 16 + ln;
      float bv = bias[j0 + jcol];
#pragma unroll
      for (int r = 0; r < 4; r++) {
        int mrow = rh * 32 + i * 16 + qd * 4 + r;
        sh[mrow * 136 + jcol] = (short)f2bf((acc[i][j][r] + bv) * qscale);
      }
    }
  __syncthreads();
  if (!is_kv) {
#pragma unroll
    for (int p = 0; p < 4; p++) {
      int u = tid + p * 256;
      int row = u >> 4, c = (u & 15) * 8;
      int hh = ((j0 + c) >> 6) & 7, d0 = c & 63;
      *reinterpret_cast<uint4*>(qhi + ((size_t)hh * N_TOK + m0 + row) * DH + d0) =
          *reinterpret_cast<const uint4*>(&sh[row * 136 + c]);
    }
  } else {
    const int sel = j0 >> 9;  // 1 = K, 2 = V
    unsigned short* dstc = (sel == 1) ? kc : vc;
#pragma unroll
    for (int p = 0; p < 4; p++) {
      int u = tid + p * 256;
      int row = u >> 4, c = (u & 15) * 8;
      int hh = ((j0 + c) >> 6) & 7, d0 = c & 63;
      *reinterpret_cast<uint4*>(
          dstc + (((size_t)kk * 8 + hh) * KVPAD + mloc + row) * DH + d0) =
          *reinterpret_cast<const uint4*>(&sh[row * 136 + c]);
    }
  }
}

// ---------------------------------------------------------------------------
// MFMA flash attention (R5/R10-validated): static tail, compact K/V.
// ---------------------------------------------------------------------------
__global__ __launch_bounds__(256) void flash_mfma(
    const unsigned short* __restrict__ qhi, const unsigned short* __restrict__ kc,
    const unsigned short* __restrict__ vc, const int* __restrict__ clusters,
    unsigned short* __restrict__ xahi) {
  __shared__ short Ks[64 * 72];
  __shared__ short Vs[64 * 72];
  __shared__ short Ps[128 * 72];
  const int tid = threadIdx.x;
  const int qb = blockIdx.x, kk = blockIdx.y, h = blockIdx.z;
  const int wave = tid >> 6, lane = tid & 63;
  const int ln = lane & 15, qd = lane >> 4;

  const int q_local0 = qb * 128;
  const int frame = clusters[kk * 4 + (q_local0 >> 9)];
  const int tokbase = frame * TPF + (q_local0 & 511);
  const size_t kvbase = ((size_t)kk * 8 + h) * KVPAD * DH;

  frag16 qa_h[2][2];
#pragma unroll
  for (int mt = 0; mt < 2; mt++) {
    const int tok_m = tokbase + wave * 32 + mt * 16 + ln;
    const unsigned short* qr_h = qhi + ((size_t)h * N_TOK + tok_m) * DH;
#pragma unroll
    for (int s = 0; s < 2; s++)
      qa_h[mt][s] = *reinterpret_cast<const frag16*>(qr_h + s * 32 + qd * 8);
  }

  f32x4 acc_o[2][4] = {};
  float lsum[2][4] = {};

  for (int t0 = 0; t0 < 192; t0 += 64) {
#pragma unroll
    for (int i = 0; i < 2; i++) {
      int u = tid + i * 256;
      int r = u >> 3, oct = u & 7;
      *reinterpret_cast<frag16*>(&Ks[r * 72 + oct * 8]) =
          *reinterpret_cast<const frag16*>(kc + kvbase + (size_t)(t0 + r) * DH + oct * 8);
    }
    {
      int tk = (tid & 15) * 4, td = (tid >> 4) * 4;
      uint2 w2[4];
#pragma unroll
      for (int i = 0; i < 4; i++)
        w2[i] = *reinterpret_cast<const uint2*>(vc + kvbase + (size_t)(t0 + tk + i) * DH + td);
#pragma unroll
      for (int dd = 0; dd < 4; dd++) {
        unsigned s0 = (dd < 2) ? (w2[0].x >> (16 * dd)) : (w2[0].y >> (16 * (dd - 2)));
        unsigned s1 = (dd < 2) ? (w2[1].x >> (16 * dd)) : (w2[1].y >> (16 * (dd - 2)));
        unsigned s2 = (dd < 2) ? (w2[2].x >> (16 * dd)) : (w2[2].y >> (16 * (dd - 2)));
        unsigned s3 = (dd < 2) ? (w2[3].x >> (16 * dd)) : (w2[3].y >> (16 * (dd - 2)));
        *reinterpret_cast<uint2*>(&Vs[(td + dd) * 72 + tk]) =
            make_uint2((s0 & 0xffffu) | (s1 << 16), (s2 & 0xffffu) | (s3 << 16));
      }
    }
    __syncthreads();

#pragma unroll
    for (int mt = 0; mt < 2; mt++) {
      f32x4 sacc[4] = {};
#pragma unroll
      for (int c = 0; c < 4; c++) {
#pragma unroll
        for (int s = 0; s < 2; s++) {
          frag16 bh = *reinterpret_cast<const frag16*>(&Ks[(c * 16 + ln) * 72 + s * 32 + qd * 8]);
          sacc[c] = __builtin_amdgcn_mfma_f32_16x16x32_bf16(qa_h[mt][s], bh, sacc[c], 0, 0, 0);
        }
      }
#pragma unroll
      for (int c = 0; c < 4; c++) {
#pragma unroll
        for (int r = 0; r < 4; r++) {
          float p = __expf(sacc[c][r]);
          lsum[mt][r] += p;
          Ps[(wave * 32 + mt * 16 + qd * 4 + r) * 72 + c * 16 + ln] = (short)f2bf(p);
        }
      }
    }

#pragma unroll
    for (int mt = 0; mt < 2; mt++)
#pragma unroll
      for (int s = 0; s < 2; s++) {
        frag16 pa = *reinterpret_cast<const frag16*>(
            &Ps[(wave * 32 + mt * 16 + ln) * 72 + s * 32 + qd * 8]);
#pragma unroll
        for (int dt = 0; dt < 4; dt++) {
          frag16 vb = *reinterpret_cast<const frag16*>(&Vs[(dt * 16 + ln) * 72 + s * 32 + qd * 8]);
          acc_o[mt][dt] = __builtin_amdgcn_mfma_f32_16x16x32_bf16(pa, vb, acc_o[mt][dt], 0, 0, 0);
        }
      }
    __syncthreads();
  }

  {
    const int t0 = 192;
#pragma unroll
    for (int i = 0; i < 2; i++) {
      int u = tid + i * 256;
      int r = u >> 3, oct = u & 7;
      *reinterpret_cast<frag16*>(&Ks[r * 72 + oct * 8]) =
          *reinterpret_cast<const frag16*>(kc + kvbase + (size_t)(t0 + r) * DH + oct * 8);
    }
    {
      int tk = (tid & 15) * 4, td = (tid >> 4) * 4;
      uint2 w2[4];
#pragma unroll
      for (int i = 0; i < 4; i++)
        w2[i] = *reinterpret_cast<const uint2*>(vc + kvbase + (size_t)(t0 + tk + i) * DH + td);
#pragma unroll
      for (int dd = 0; dd < 4; dd++) {
        unsigned s0 = (dd < 2) ? (w2[0].x >> (16 * dd)) : (w2[0].y >> (16 * (dd - 2)));
        unsigned s1 = (dd < 2) ? (w2[1].x >> (16 * dd)) : (w2[1].y >> (16 * (dd - 2)));
        unsigned s2 = (dd < 2) ? (w2[2].x >> (16 * dd)) : (w2[2].y >> (16 * (dd - 2)));
        unsigned s3 = (dd < 2) ? (w2[3].x >> (16 * dd)) : (w2[3].y >> (16 * (dd - 2)));
        *reinterpret_cast<uint2*>(&Vs[(td + dd) * 72 + tk]) =
            make_uint2((s0 & 0xffffu) | (s1 << 16), (s2 & 0xffffu) | (s3 << 16));
      }
    }
    __syncthreads();

#pragma unroll
    for (int mt = 0; mt < 2; mt++) {
      f32x4 sacc = {};
#pragma unroll
      for (int s = 0; s < 2; s++) {
        frag16 bh = *reinterpret_cast<const frag16*>(&Ks[ln * 72 + s * 32 + qd * 8]);
        sacc = __builtin_amdgcn_mfma_f32_16x16x32_bf16(qa_h[mt][s], bh, sacc, 0, 0, 0);
      }
#pragma unroll
      for (int r = 0; r < 4; r++) {
        float p = (ln < 12) ? __expf(sacc[r]) : 0.f;
        lsum[mt][r] += p;
        int prow = (wave * 32 + mt * 16 + qd * 4 + r) * 72;
        Ps[prow + ln] = (short)f2bf(p);
        Ps[prow + 16 + ln] = 0;
      }
    }

#pragma unroll
    for (int mt = 0; mt < 2; mt++) {
      frag16 pa = *reinterpret_cast<const frag16*>(
          &Ps[(wave * 32 + mt * 16 + ln) * 72 + qd * 8]);
#pragma unroll
      for (int dt = 0; dt < 4; dt++) {
        frag16 vb = *reinterpret_cast<const frag16*>(&Vs[(dt * 16 + ln) * 72 + qd * 8]);
        acc_o[mt][dt] = __builtin_amdgcn_mfma_f32_16x16x32_bf16(pa, vb, acc_o[mt][dt], 0, 0, 0);
      }
    }
  }

#pragma unroll
  for (int mt = 0; mt < 2; mt++)
#pragma unroll
    for (int r = 0; r < 4; r++) {
      float l = lsum[mt][r];
      l += __shfl_xor(l, 1);
      l += __shfl_xor(l, 2);
      l += __shfl_xor(l, 4);
      l += __shfl_xor(l, 8);
      lsum[mt][r] = 1.f / l;
    }

#pragma unroll
  for (int mt = 0; mt < 2; mt++)
#pragma unroll
    for (int dt = 0; dt < 4; dt++)
#pragma unroll
      for (int r = 0; r < 4; r++)
        Ps[(wave * 32 + mt * 16 + qd * 4 + r) * 72 + dt * 16 + ln] =
            (short)f2bf(acc_o[mt][dt][r] * lsum[mt][r]);
  __syncthreads();
#pragma unroll
  for (int p = 0; p < 4; p++) {
    int u = tid + p * 256;
    int row = u >> 3, c = (u & 7) * 8;
    *reinterpret_cast<uint4*>(xahi + (size_t)(tokbase + row) * C_DIM + h * DH + c) =
        *reinterpret_cast<const uint4*>(&Ps[row * 72 + c]);
  }
}

// ---------------------------------------------------------------------------
// Projection GEMM (R5/R10-validated): 64x128, reg-dbuf, 512 blocks.
// ---------------------------------------------------------------------------
__global__ __launch_bounds__(256) void gemm_proj(
    const unsigned short* __restrict__ Ahi, const unsigned short* __restrict__ Bhi,
    const float* __restrict__ bias, float* __restrict__ out) {
  __shared__ short pool[12288];
  short* As = pool;
  short* Bs = pool + 4096;
  const int tid = threadIdx.x;
  const int bid = blockIdx.x;
  const int grp = bid / 32;
  const int rem = bid - grp * 32;
  const int jblk = rem >> 3;
  const int m_idx = grp * 8 + (rem & 7);
  const int j0 = jblk * 128;
  const int m0 = m_idx * 64;
  const int wave = tid >> 6, lane = tid & 63;
  const int rh = wave >> 1, ch = wave & 1;
  const int qd = lane >> 4, ln = lane & 15;

  const int arow = tid & 63, ap = tid >> 6;
  const int brow = tid & 127, bp = tid >> 7;
  const unsigned short* pA = Ahi + (size_t)(m0 + arow) * C_DIM + ap * 8;
  const unsigned short* pB0 = Bhi + (size_t)(j0 + brow) * C_DIM + bp * 8;
  const unsigned short* pB1 = pB0 + 16;

  f32x4 acc[2][4] = {};

  uint4 ra = *reinterpret_cast<const uint4*>(pA);
  uint4 rb0 = *reinterpret_cast<const uint4*>(pB0);
  uint4 rb1 = *reinterpret_cast<const uint4*>(pB1);
  *reinterpret_cast<uint4*>(&As[ap * 512 + arow * 8]) = ra;
  *reinterpret_cast<uint4*>(&Bs[bp * 1024 + brow * 8]) = rb0;
  *reinterpret_cast<uint4*>(&Bs[(bp + 2) * 1024 + brow * 8]) = rb1;
  __syncthreads();

  int cur = 0;
#pragma unroll
  for (int it = 0; it < 16; it++) {
    if (it < 15) {
      int k = (it + 1) * 32;
      ra = *reinterpret_cast<const uint4*>(pA + k);
      rb0 = *reinterpret_cast<const uint4*>(pB0 + k);
      rb1 = *reinterpret_cast<const uint4*>(pB1 + k);
    }
    frag16 a_h[2], b_h[4];
#pragma unroll
    for (int i = 0; i < 2; i++)
      a_h[i] = *reinterpret_cast<const frag16*>(&As[cur * 2048 + qd * 512 + (rh * 32 + i * 16 + ln) * 8]);
#pragma unroll
    for (int j = 0; j < 4; j++)
      b_h[j] = *reinterpret_cast<const frag16*>(&Bs[cur * 4096 + qd * 1024 + (ch * 64 + j * 16 + ln) * 8]);
#pragma unroll
    for (int i = 0; i < 2; i++)
#pragma unroll
      for (int j = 0; j < 4; j++)
        acc[i][j] = __builtin_amdgcn_mfma_f32_16x16x32_bf16(a_h[i], b_h[j], acc[i][j], 0, 0, 0);
    if (it < 15) {
      int nxt = cur ^ 1;
      *reinterpret_cast<uint4*>(&As[nxt * 2048 + ap * 512 + arow * 8]) = ra;
      *reinterpret_cast<uint4*>(&Bs[nxt * 4096 + bp * 1024 + brow * 8]) = rb0;
      *reinterpret_cast<uint4*>(&Bs[nxt * 4096 + (bp + 2) * 1024 + brow * 8]) = rb1;
      __syncthreads();
      cur = nxt;
    }
  }

  float* sh32 = reinterpret_cast<float*>(pool);  // 64 x 68
#pragma unroll
  for (int chp = 0; chp < 2; chp++) {
    __syncthreads();
    if (ch == chp) {
#pragma unroll
      for (int i = 0; i < 2; i++)
#pragma unroll
        for (int j = 0; j < 4; j++) {
          int jcol = j * 16 + ln;
          float bv = bias[j0 + chp * 64 + jcol];
#pragma unroll
          for (int r = 0; r < 4; r++)
            sh32[(rh * 32 + i * 16 + qd * 4 + r) * 68 + jcol] = acc[i][j][r] + bv;
        }
    }
    __syncthreads();
#pragma unroll
    for (int p = 0; p < 4; p++) {
      int u = tid + p * 256;
      int row = u >> 4, c4 = (u & 15) * 4;
      *reinterpret_cast<float4*>(out + (size_t)(m0 + row) * C_DIM + j0 + chp * 64 + c4) =
          *reinterpret_cast<const float4*>(&sh32[row * 68 + c4]);
    }
  }
}

// ---------------------------------------------------------------------------
extern "C" void kernel_launch(void* const* d_in, const int* in_sizes, int n_in,
                              void* d_out, int out_size, void* d_ws, size_t ws_size,
                              hipStream_t stream) {
  const float* x = (const float*)d_in[0];
  const float* w_qkv = (const float*)d_in[1];
  const float* b_qkv = (const float*)d_in[2];
  const float* w_proj = (const float*)d_in[3];
  const float* b_proj = (const float*)d_in[4];
  const int* keyframes = (const int*)d_in[5];
  const int* clusters = (const int*)d_in[6];
  float* out = (float*)d_out;
  float* ws = (float*)d_ws;

  unsigned short* wqh = (unsigned short*)(ws + WS_WQH);
  unsigned short* wph = (unsigned short*)(ws + WS_WPH);
  unsigned short* qhi = (unsigned short*)(ws + WS_QHI);
  unsigned short* kc = (unsigned short*)(ws + WS_KC);
  unsigned short* vc = (unsigned short*)(ws + WS_VC);
  unsigned short* xahi = (unsigned short*)(ws + WS_XAHI);
  float* xbarp = ws + WS_XBARP;
  float* qbar = ws + WS_QBAR;
  float* g = ws + WS_G;
  float* agg = ws + WS_AGG;

  // 1. xbar partials (64 blocks)
  prep_xbar<<<64, 256, 0, stream>>>(x, keyframes, xbarp);
  // 2. qbar, wave-parallel (256 blocks)
  qbar_wide<<<256, 256, 0, stream>>>(w_qkv, b_qkv, xbarp, qbar);
  // 3. g, parallel (128 blocks)
  g_wide<<<128, 256, 0, stream>>>(w_qkv, qbar, g);
  // 4. agg (2048) + weight cvt (1024) in one launch
  agg_wcvt<<<3072, 256, 0, stream>>>(x, g, agg, w_qkv, w_proj, wqh, wph);
  // 5. Q GEMM (64x128, 512 blk) + KV GEMM 64x128 with in-block topk (128 blk)
  gemm_qkv2<<<640, 256, 0, stream>>>(x, wqh, b_qkv, agg, qhi, kc, vc);
  // 6. fused MFMA attention
  flash_mfma<<<dim3(MPC / 128, KCLUST, NH), 256, 0, stream>>>(
      qhi, kc, vc, clusters, xahi);
  // 7. projection GEMM
  gemm_proj<<<512, 256, 0, stream>>>(xahi, wph, b_proj, out);
}